// Round 9
// baseline (1880.492 us; speedup 1.0000x reference)
//
#include <hip/hip_runtime.h>

// Residual VQ: B=32, D=64, L=4096, NCB=4, K=512.
// out: z_q_aggregated [B][NCB][D][L] f32, then indices [B][L][NCB] (as f32).
//
// Bit-exact reproduction of the reference float32 pipeline (validated absmax=0):
//   dot[t][k]: mul-init + single-accumulator FMA chain, d ascending 0..63
//   sx, se:    numpy pairwise 8-accumulator sum of squares, exact bracketing
//   d2 = (sx - 2*dot) + se     (two f32 roundings; 2*dot exact)
//   argmin:    first minimum (lowest k)
//   cascade:   x_res -= e[idx]; z_q += e[idx] in plain f32
//
// v9: k-split x2 for TLP. The grid only has 2048 waves (2/SIMD) at one
// token/lane, which cannot hide L2 latency (v7/v8: VALUBusy 52%, busy time
// 500us vs 218us FMA floor). Wave pairs share 64 tokens: wave A scans
// k<256, B scans k>=256 -> 4096 waves = 4/SIMD; per-cb merge via LDS with
// index tie-break (== global first-min since A's k-range is lower). 8-chain
// d4-major scan amortizes quartet-head latency. zq lives in LDS (A-waves),
// evicting v8's scratch spill (VGPR 84 proved zq was demoted). launch_bounds
// (256,4) caps VGPR at 128 to lock 4 waves/SIMD.

#define LL   4096
#define DD   64
#define KK   512
#define NCB  4
#define NTHR 256

#define ZQ_ELEMS (32LL * NCB * DD * LL)   // 33,554,432 floats

// numpy pairwise sum of squares, n=64, exact op order (8 accumulators)
__device__ __forceinline__ float np_pairwise_sq64(const float* p) {
#pragma clang fp contract(off)
    float r[8];
#pragma unroll
    for (int j = 0; j < 8; ++j) { float s = p[j] * p[j]; r[j] = s; }
#pragma unroll
    for (int i = 8; i < 64; i += 8)
#pragma unroll
        for (int j = 0; j < 8; ++j) { float s = p[i + j] * p[i + j]; r[j] = r[j] + s; }
    return ((r[0] + r[1]) + (r[2] + r[3])) + ((r[4] + r[5]) + (r[6] + r[7]));
}

// ---------------- Kernel A: se[c][k] = np.sum(e*e, -1) ----------------
__global__ void se_kernel(const float* __restrict__ cb, float* __restrict__ se) {
    int t = blockIdx.x * blockDim.x + threadIdx.x;
    if (t >= NCB * KK) return;
    se[t] = np_pairwise_sq64(cb + (size_t)t * DD);
}

// ---------------- Main kernel ----------------
__global__ __launch_bounds__(NTHR, 4) void rvq_kernel(const float* __restrict__ x_in,
                                                      const float* __restrict__ cb,
                                                      const float* __restrict__ se,
                                                      float* __restrict__ out) {
    __shared__ float zq_lds[2][DD][64];   // A-waves' z_q accumulator (32 KB)
    __shared__ float exv[4][64];          // argmin exchange: values
    __shared__ int   exi[4][64];          // argmin exchange: indices

    const int tid  = threadIdx.x;
    const int lane = tid & 63;
    const int wid  = tid >> 6;
    const int ts   = wid >> 1;     // token-set 0/1 within block
    const int half = wid & 1;      // k-half this wave scans

    const int tok = blockIdx.x * 128 + ts * 64 + lane;   // 1024 blocks x 128 tokens
    const int b   = tok >> 12;
    const int l   = tok & 4095;

    // ---- load this lane's token column: x[d] = x_in[b][d][l] (coalesced) ----
    float x[DD];
    {
        const float* xb = x_in + (size_t)b * DD * LL + l;
#pragma unroll
        for (int d = 0; d < DD; ++d) x[d] = xb[(size_t)d * LL];
    }

    // zero the zq accumulator (wave-private LDS slice; no barrier needed)
    if (half == 0) {
#pragma unroll
        for (int d = 0; d < DD; ++d) zq_lds[ts][d][lane] = 0.f;
    }

    const int kbase = half * 256;

#pragma unroll 1
    for (int c = 0; c < NCB; ++c) {
        // ---- sx: numpy pairwise sum of squares, lane-local, exact order ----
        float sxv;
        {
#pragma clang fp contract(off)
            float r[8];
#pragma unroll
            for (int j = 0; j < 8; ++j) { float s = x[j] * x[j]; r[j] = s; }
#pragma unroll
            for (int i = 8; i < 64; i += 8)
#pragma unroll
                for (int j = 0; j < 8; ++j) { float s = x[i + j] * x[i + j]; r[j] = r[j] + s; }
            sxv = ((r[0] + r[1]) + (r[2] + r[3])) + ((r[4] + r[5]) + (r[6] + r[7]));
        }

        float bestv = __builtin_inff();
        int   besti = kbase;

        // ---- half-codebook scan: 8 independent mul-init+FMA chains,
        // d4-major straight-line body (128 loads pipelined vs 512 FMAs). ----
#pragma unroll 1
        for (int k0 = kbase; k0 < kbase + 256; k0 += 8) {
            const float* ep = cb + ((size_t)(c * KK + k0)) * DD;
            float dot[8];
            {   // d4 = 0: mul-init (== fmaf into +0), then ascending fmaf
#pragma unroll
                for (int j = 0; j < 8; ++j) {
                    const float4 e = *reinterpret_cast<const float4*>(ep + j * DD);
                    dot[j] = x[0] * e.x;
                    dot[j] = fmaf(x[1], e.y, dot[j]);
                    dot[j] = fmaf(x[2], e.z, dot[j]);
                    dot[j] = fmaf(x[3], e.w, dot[j]);
                }
            }
#pragma unroll
            for (int d4 = 1; d4 < 16; ++d4) {
#pragma unroll
                for (int j = 0; j < 8; ++j) {
                    const float4 e = *reinterpret_cast<const float4*>(ep + j * DD + 4 * d4);
                    dot[j] = fmaf(x[4 * d4 + 0], e.x, dot[j]);
                    dot[j] = fmaf(x[4 * d4 + 1], e.y, dot[j]);
                    dot[j] = fmaf(x[4 * d4 + 2], e.z, dot[j]);
                    dot[j] = fmaf(x[4 * d4 + 3], e.w, dot[j]);
                }
            }

            // fold: d2 = (sx - 2*dot) + se, two f32 roundings, strict-< first-min
            {
#pragma clang fp contract(off)
                const float4 sa = *reinterpret_cast<const float4*>(se + c * KK + k0);
                const float4 sb = *reinterpret_cast<const float4*>(se + c * KK + k0 + 4);
                const float sev[8] = {sa.x, sa.y, sa.z, sa.w, sb.x, sb.y, sb.z, sb.w};
#pragma unroll
                for (int j = 0; j < 8; ++j) {
                    const float twod = 2.0f * dot[j];     // exact (x2)
                    const float d2 = (sxv - twod) + sev[j];
                    if (d2 < bestv) { bestv = d2; besti = k0 + j; }
                }
            }
        }

        // ---- cross-wave merge (A holds k<256, B holds k>=256).
        // take partner iff (ov < v) || (ov == v && oi < i) == global first-min ----
        exv[wid][lane] = bestv;
        exi[wid][lane] = besti;
        __syncthreads();
        {
            const float ov = exv[wid ^ 1][lane];
            const int   oi = exi[wid ^ 1][lane];
            if (ov < bestv || (ov == bestv && oi < besti)) { bestv = ov; besti = oi; }
        }
        __syncthreads();   // reads done before next cb's exchange writes

        // ---- residual update (both waves, keeps x copies identical) +
        // z_q accumulate/store (A-waves only, zq in LDS) ----
        {
#pragma clang fp contract(off)
            const float* er = cb + ((size_t)(c * KK) + besti) * DD;
            if (half == 0) {
                float* zo = out + (((size_t)b * NCB + c) * DD) * LL + l;
#pragma unroll
                for (int d4 = 0; d4 < DD; d4 += 4) {
                    const float4 ev = *reinterpret_cast<const float4*>(er + d4);
                    x[d4 + 0] = x[d4 + 0] - ev.x;
                    x[d4 + 1] = x[d4 + 1] - ev.y;
                    x[d4 + 2] = x[d4 + 2] - ev.z;
                    x[d4 + 3] = x[d4 + 3] - ev.w;
                    const float z0 = zq_lds[ts][d4 + 0][lane] + ev.x;
                    const float z1 = zq_lds[ts][d4 + 1][lane] + ev.y;
                    const float z2 = zq_lds[ts][d4 + 2][lane] + ev.z;
                    const float z3 = zq_lds[ts][d4 + 3][lane] + ev.w;
                    zq_lds[ts][d4 + 0][lane] = z0;  zo[(size_t)(d4 + 0) * LL] = z0;
                    zq_lds[ts][d4 + 1][lane] = z1;  zo[(size_t)(d4 + 1) * LL] = z1;
                    zq_lds[ts][d4 + 2][lane] = z2;  zo[(size_t)(d4 + 2) * LL] = z2;
                    zq_lds[ts][d4 + 3][lane] = z3;  zo[(size_t)(d4 + 3) * LL] = z3;
                }
                out[ZQ_ELEMS + ((size_t)b * LL + l) * NCB + c] = (float)besti;
            } else {
#pragma unroll
                for (int d4 = 0; d4 < DD; d4 += 4) {
                    const float4 ev = *reinterpret_cast<const float4*>(er + d4);
                    x[d4 + 0] = x[d4 + 0] - ev.x;
                    x[d4 + 1] = x[d4 + 1] - ev.y;
                    x[d4 + 2] = x[d4 + 2] - ev.z;
                    x[d4 + 3] = x[d4 + 3] - ev.w;
                }
            }
        }
    }
}

extern "C" void kernel_launch(void* const* d_in, const int* in_sizes, int n_in,
                              void* d_out, int out_size, void* d_ws, size_t ws_size,
                              hipStream_t stream) {
    const float* x_in = (const float*)d_in[0];
    const float* cb   = (const float*)d_in[1];
    float* out = (float*)d_out;
    float* se  = (float*)d_ws;   // NCB*KK floats = 8 KB scratch

    se_kernel<<<dim3((NCB * KK + 255) / 256), dim3(256), 0, stream>>>(cb, se);
    rvq_kernel<<<dim3((32 * LL) / 128), dim3(NTHR), 0, stream>>>(x_in, cb, se, out);
}